// Round 10
// baseline (280.127 us; speedup 1.0000x reference)
//
#include <hip/hip_runtime.h>
#include <math.h>

constexpr int N_  = 50000;
constexpr int E_  = 500000;
constexpr int NB_ = (N_ + 255) / 256;   // 196 scan blocks

typedef unsigned short u16;
typedef unsigned int u32;
typedef short short8 __attribute__((ext_vector_type(8)));
typedef __bf16 bf16x8 __attribute__((ext_vector_type(8)));
typedef float f32x4 __attribute__((ext_vector_type(4)));
typedef short short4v __attribute__((ext_vector_type(4)));

#define DINL __device__ __forceinline__

DINL float gelu_f(float x) { return 0.5f * x * (1.f + erff(x * 0.70710678118654752f)); }
DINL float sigmoid_f(float x) { return 1.f / (1.f + expf(-x)); }
DINL u16 f2b(float x) {            // f32 -> bf16 RNE
  unsigned u = __float_as_uint(x);
  return (u16)((u + 0x7FFFu + ((u >> 16) & 1u)) >> 16);
}
DINL float b2f(u16 b) { return __uint_as_float(((unsigned)b) << 16); }

// butterfly sum over each 32-lane half: 4 DPP stages (VALU pipe) + 1 ds_swizzle (xor16)
template <int CTRL>
DINL float dpp_add(float c) {
  int p = __builtin_amdgcn_update_dpp(0, __builtin_bit_cast(int, c), CTRL, 0xf, 0xf, false);
  return c + __builtin_bit_cast(float, p);
}
DINL float half_reduce(float c) {
  c = dpp_add<0xB1>(c);    // quad_perm [1,0,3,2]  : xor1
  c = dpp_add<0x4E>(c);    // quad_perm [2,3,0,1]  : xor2
  c = dpp_add<0x141>(c);   // row_half_mirror      : xor4
  c = dpp_add<0x140>(c);   // row_mirror           : xor8
  int p = __builtin_amdgcn_ds_swizzle(__builtin_bit_cast(int, c), 0x401F);  // xor16
  return c + __builtin_bit_cast(float, p);
}

// ================= CSR build =================
__global__ void deg_int_kernel(const int* __restrict__ dst, int* __restrict__ deg) {
  int t = blockIdx.x * 256 + threadIdx.x;
  if (t < E_) atomicAdd(&deg[dst[t]], 1);
}

__global__ __launch_bounds__(256) void scan_local(const int* __restrict__ deg,
    int* __restrict__ rowptr, int* __restrict__ bsum) {
  __shared__ int sums[4];
  const int tid = threadIdx.x, lane = tid & 63, wid = tid >> 6;
  const int i = blockIdx.x * 256 + tid;
  int v = (i < N_) ? deg[i] : 0;
  int x = v;
#pragma unroll
  for (int o = 1; o < 64; o <<= 1) { int y = __shfl_up(x, o); if (lane >= o) x += y; }
  if (lane == 63) sums[wid] = x;
  __syncthreads();
  int woff = 0;
#pragma unroll
  for (int w = 0; w < 3; ++w) if (w < wid) woff += sums[w];
  if (i < N_) rowptr[i] = x - v + woff;
  if (tid == 255) bsum[blockIdx.x] = woff + x;
}

__global__ __launch_bounds__(256) void scan_block(const int* __restrict__ bsum,
                                                  int* __restrict__ bpre) {
  __shared__ int sums[4];
  const int tid = threadIdx.x, lane = tid & 63, wid = tid >> 6;
  int v = (tid < NB_) ? bsum[tid] : 0;
  int x = v;
#pragma unroll
  for (int o = 1; o < 64; o <<= 1) { int y = __shfl_up(x, o); if (lane >= o) x += y; }
  if (lane == 63) sums[wid] = x;
  __syncthreads();
  int woff = 0;
#pragma unroll
  for (int w = 0; w < 3; ++w) if (w < wid) woff += sums[w];
  if (tid < NB_) bpre[tid] = x - v + woff;
  if (tid == 255) bpre[NB_] = woff + x;
}

__global__ __launch_bounds__(256) void scan_add(int* __restrict__ rowptr,
                                                const int* __restrict__ bpre) {
  int i = blockIdx.x * 256 + threadIdx.x;
  if (i < N_) rowptr[i] += bpre[i >> 8];
  else if (i == N_) rowptr[N_] = bpre[NB_];
}

__global__ void csr_fill(const int* __restrict__ src, const int* __restrict__ dst,
                         const int* __restrict__ rowptr, int* __restrict__ cursor,
                         int* __restrict__ colsrc) {
  int e = blockIdx.x * 256 + threadIdx.x;
  if (e >= E_) return;
  int d = dst[e];
  int pos = rowptr[d] + atomicAdd(&cursor[d], 1);
  colsrc[pos] = src[e];
}

// ================= packing =================
__global__ __launch_bounds__(256) void pack_feat(const float* __restrict__ f,
                                                 u16* __restrict__ o) {
  int t = blockIdx.x * 256 + threadIdx.x;
  float4 v = ((const float4*)f)[t];
  short4v r;
  r[0] = (short)f2b(v.x); r[1] = (short)f2b(v.y);
  r[2] = (short)f2b(v.z); r[3] = (short)f2b(v.w);
  ((short4v*)o)[t] = r;
}

// pack weights into MFMA fragment order (identical for A- and B-operand use):
// dst[((ct*(K/32)+ks)*64+lane)*8+j] = W[ks*32+(lane>>4)*8+j][ct*16+(lane&15)]
__global__ __launch_bounds__(256) void pack_w(
    const float* __restrict__ Wmt, const float* __restrict__ Wms,
    const float* __restrict__ W1s, const float* __restrict__ W1n,
    const float* __restrict__ W2s, const float* __restrict__ W2n,
    const float* __restrict__ g1Ws, const float* __restrict__ g1Wd,
    const float* __restrict__ g2Ws, const float* __restrict__ g2Wd,
    const float* __restrict__ W3, u16* __restrict__ dst) {
  int e = blockIdx.x * 256 + threadIdx.x;
  const float *Wa, *Wb = nullptr;
  int K1, K2 = 0, Ca, Cb = 0, st;
  if (e < 16384)       { Wa = Wmt;  K1 = 128; Ca = 128;           st = 0; }
  else if (e < 32768)  { Wa = Wms;  K1 = 128; Ca = 128;           st = 16384; }
  else if (e < 49152)  { Wa = W1s;  Wb = W1n; K1 = 128; K2 = 128; Ca = 64;  st = 32768; }
  else if (e < 57344)  { Wa = W2s;  Wb = W2n; K1 = 64;  K2 = 64;  Ca = 64;  st = 49152; }
  else if (e < 90112)  { Wa = g1Ws; Wb = g1Wd; K1 = 128; Ca = 128; Cb = 128; st = 57344; }
  else if (e < 106496) { Wa = g2Ws; Wb = g2Wd; K1 = 64;  Ca = 128; Cb = 128; st = 90112; }
  else                 { Wa = W3;   K1 = 192; Ca = 64;            st = 106496; }
  int el = e - st;
  int Kt = K1 + K2;
  int ct = el / (Kt * 16);
  int rem = el - ct * Kt * 16;
  int ks = rem >> 9, rem2 = rem & 511, lane = rem2 >> 3, j = rem2 & 7;
  int k = ks * 32 + ((lane >> 4) << 3) + j;
  int c = ct * 16 + (lane & 15);
  float v;
  if (k < K1) v = (c < Ca) ? Wa[k * Ca + c] : Wb[k * Cb + (c - Ca)];
  else        v = Wb[(k - K1) * Ca + c];
  dst[e] = f2b(v);
}

// ================= MFMA GEMM =================
// Swapped operands: W-frag is the MFMA A-operand, activation-frag is B.
// D transposed: lane l holds node (l&15), output cols (l>>4)*4+r -> short4 stores.
// LDS XOR-swizzled: 16B-chunk index ^= (row & 7).
template <int K1, int K2, int C, int EPI>
__global__ __launch_bounds__(256) void gemm_mfma(
    const u16* __restrict__ A1, const u16* __restrict__ A2,
    const u16* __restrict__ Wp, const float* __restrict__ bias,
    const float* __restrict__ bias2, const float* __restrict__ mulf,
    void* __restrict__ outv, void* __restrict__ outv2) {
  constexpr int K = K1 + K2, KS = K / 32, CT4 = C / 64;
  constexpr int NCH1 = K1 / 8, NCH2 = K2 / 8;
  __shared__ u16 alds[64 * K];
  const int tid = threadIdx.x;
  const int w = tid >> 6, l = tid & 63;
  const int wr0 = blockIdx.x * 64;

  short8 wfrag[KS][CT4];
#pragma unroll
  for (int ks = 0; ks < KS; ++ks)
#pragma unroll
    for (int c4 = 0; c4 < CT4; ++c4)
      wfrag[ks][c4] = *(const short8*)(Wp +
          ((size_t)((w * CT4 + c4) * KS + ks) * 64 + l) * 8);

  for (int i = tid; i < 64 * NCH1; i += 256) {
    int rr = i / NCH1, kc = i % NCH1;
    int gr = wr0 + rr; if (gr >= N_) gr = N_ - 1;
    short8 v = *(const short8*)(A1 + (long)gr * K1 + kc * 8);
    *(short8*)&alds[rr * K + ((kc ^ (rr & 7)) << 3)] = v;
  }
  if constexpr (K2 > 0) {
    for (int i = tid; i < 64 * NCH2; i += 256) {
      int rr = i / NCH2, kc = i % NCH2;
      int gr = wr0 + rr; if (gr >= N_) gr = N_ - 1;
      short8 v = *(const short8*)(A2 + (long)gr * K2 + kc * 8);
      *(short8*)&alds[rr * K + (((NCH1 + kc) ^ (rr & 7)) << 3)] = v;
    }
  }
  __syncthreads();

  f32x4 acc[4][CT4];
#pragma unroll
  for (int rg = 0; rg < 4; ++rg)
#pragma unroll
    for (int c4 = 0; c4 < CT4; ++c4) acc[rg][c4] = (f32x4){0.f, 0.f, 0.f, 0.f};

#pragma unroll
  for (int ks = 0; ks < KS; ++ks) {
#pragma unroll
    for (int rg = 0; rg < 4; ++rg) {
      const int nr = rg * 16 + (l & 15);
      const int ch = (ks * 4 + (l >> 4)) ^ (nr & 7);
      short8 av = *(const short8*)&alds[nr * K + (ch << 3)];
      bf16x8 bf = __builtin_bit_cast(bf16x8, av);
#pragma unroll
      for (int c4 = 0; c4 < CT4; ++c4)
        acc[rg][c4] = __builtin_amdgcn_mfma_f32_16x16x32_bf16(
            __builtin_bit_cast(bf16x8, wfrag[ks][c4]), bf, acc[rg][c4], 0, 0, 0);
    }
  }

  const int colq = (l >> 4) << 2;            // col offset within 16-col tile
  if constexpr (EPI == 0) {
    u16* out = (u16*)outv;
#pragma unroll
    for (int rg = 0; rg < 4; ++rg) {
      int row = wr0 + rg * 16 + (l & 15);
      if (row >= N_) continue;
#pragma unroll
      for (int c4 = 0; c4 < CT4; ++c4) {
        int colb = (w * CT4 + c4) * 16 + colq;
        short4v s;
#pragma unroll
        for (int r = 0; r < 4; ++r) s[r] = (short)f2b(acc[rg][c4][r]);
        *(short4v*)(out + (long)row * C + colb) = s;
      }
    }
  } else if constexpr (EPI == 2 || EPI == 3) {
    u16* out = (u16*)outv;
    const int colb = w * 16 + colq;          // CT4 == 1
    float4 bv = *(const float4*)(bias + colb);
#pragma unroll
    for (int rg = 0; rg < 4; ++rg) {
      int row = wr0 + rg * 16 + (l & 15);
      if (row >= N_) continue;
      float4 dv;
      if constexpr (EPI == 2) dv = *(const float4*)(mulf + (long)row * C + colb);
      short4v s;
#pragma unroll
      for (int r = 0; r < 4; ++r) {
        float g = gelu_f(acc[rg][0][r] + ((const float*)&bv)[r]);
        if constexpr (EPI == 2) g *= ((const float*)&dv)[r];
        s[r] = (short)f2b(g);
      }
      *(short4v*)(out + (long)row * C + colb) = s;
    }
  } else if constexpr (EPI == 4) {          // C=64: leaky + row l2norm (f32 out)
    __shared__ float ssb[64][4];
    float* out = (float*)outv;
    const int colb = w * 16 + colq;
    float4 bv = *(const float4*)(bias + colb);
    float xv[4][4];
#pragma unroll
    for (int rg = 0; rg < 4; ++rg) {
      float ss = 0.f;
#pragma unroll
      for (int r = 0; r < 4; ++r) {
        float x = acc[rg][0][r] + ((const float*)&bv)[r];
        x = fmaxf(x, 0.01f * x);
        xv[rg][r] = x; ss += x * x;
      }
      ss += __shfl_xor(ss, 16);
      ss += __shfl_xor(ss, 32);
      if (l < 16) ssb[rg * 16 + l][w] = ss;
    }
    __syncthreads();
#pragma unroll
    for (int rg = 0; rg < 4; ++rg) {
      int nl = rg * 16 + (l & 15);
      int row = wr0 + nl;
      if (row >= N_) continue;
      float ss = ssb[nl][0] + ssb[nl][1] + ssb[nl][2] + ssb[nl][3];
      float sc = 1.f / fmaxf(sqrtf(ss), 1e-12f);
      float4 o;
#pragma unroll
      for (int r = 0; r < 4; ++r) ((float*)&o)[r] = xv[rg][r] * sc;
      *(float4*)(out + (long)row * 64 + colb) = o;
    }
  } else {                                  // EPI == 5: dual mask (C=256, K=128)
#pragma unroll
    for (int c4 = 0; c4 < CT4; ++c4) {
      const int ct = w * CT4 + c4;
      const bool lo = ct < 8;
      u16* op = lo ? (u16*)outv : (u16*)outv2;
      const int ccb = (ct & 7) * 16 + colq;
      float4 bv = *(const float4*)((lo ? bias : bias2) + ccb);
#pragma unroll
      for (int rg = 0; rg < 4; ++rg) {
        int nl = rg * 16 + (l & 15);
        int row = wr0 + nl;
        if (row >= N_) continue;
        int ch = (ccb >> 3) ^ (nl & 7);
        short4v fq = *(const short4v*)&alds[nl * K + (ch << 3) + (ccb & 7)];
        short4v s;
#pragma unroll
        for (int r = 0; r < 4; ++r) {
          float x = acc[rg][c4][r] + ((const float*)&bv)[r];
          float fv = b2f((u16)fq[r]);
          s[r] = (short)f2b(fv * sigmoid_f(x));
        }
        *(short4v*)(op + (long)row * 128 + ccb) = s;
      }
    }
  }
}

// ================= SAGE gather (scalar row bases via readfirstlane) =================
__global__ __launch_bounds__(256) void gather_bf128(const u16* __restrict__ h,
    const int* __restrict__ rowptr, const int* __restrict__ colsrc,
    u16* __restrict__ out) {
  int node = blockIdx.x * 4 + (threadIdx.x >> 6);
  int lane = threadIdx.x & 63;
  int beg = rowptr[node], end = rowptr[node + 1];
  float inv = 1.f / fmaxf((float)(end - beg), 1.f);
  const int off = 2 * lane;
  float a0 = 0.f, a1 = 0.f, b0 = 0.f, b1 = 0.f;
  int j = beg;
  for (; j + 4 <= end; j += 4) {
    const u16* p0 = h + (size_t)__builtin_amdgcn_readfirstlane(colsrc[j])     * 128;
    const u16* p1 = h + (size_t)__builtin_amdgcn_readfirstlane(colsrc[j + 1]) * 128;
    const u16* p2 = h + (size_t)__builtin_amdgcn_readfirstlane(colsrc[j + 2]) * 128;
    const u16* p3 = h + (size_t)__builtin_amdgcn_readfirstlane(colsrc[j + 3]) * 128;
    u32 v0 = *(const u32*)(p0 + off);
    u32 v1 = *(const u32*)(p1 + off);
    u32 v2 = *(const u32*)(p2 + off);
    u32 v3 = *(const u32*)(p3 + off);
    a0 += b2f((u16)(v0 & 0xffffu)) + b2f((u16)(v2 & 0xffffu));
    a1 += b2f((u16)(v0 >> 16))     + b2f((u16)(v2 >> 16));
    b0 += b2f((u16)(v1 & 0xffffu)) + b2f((u16)(v3 & 0xffffu));
    b1 += b2f((u16)(v1 >> 16))     + b2f((u16)(v3 >> 16));
  }
  for (; j < end; ++j) {
    const u16* p = h + (size_t)__builtin_amdgcn_readfirstlane(colsrc[j]) * 128;
    u32 v = *(const u32*)(p + off);
    a0 += b2f((u16)(v & 0xffffu));
    a1 += b2f((u16)(v >> 16));
  }
  a0 += b0; a1 += b1;
  u32 r = (u32)f2b(a0 * inv) | ((u32)f2b(a1 * inv) << 16);
  *(u32*)(out + (long)node * 128 + off) = r;
}

// K=64: halves process alternating edges (rows differ across halves -> no readfirstlane)
__global__ __launch_bounds__(256) void gather_bf64(const u16* __restrict__ h,
    const int* __restrict__ rowptr, const int* __restrict__ colsrc,
    u16* __restrict__ out) {
  int node = blockIdx.x * 4 + (threadIdx.x >> 6);
  int lane = threadIdx.x & 63;
  int beg = rowptr[node], end = rowptr[node + 1];
  int half = lane >> 5, cl = lane & 31;
  float a0 = 0.f, a1 = 0.f, b0 = 0.f, b1 = 0.f;
  int j = beg;
  for (; j + 4 <= end; j += 4) {
    int s0 = colsrc[j + half], s1 = colsrc[j + 2 + half];
    u32 v0 = *(const u32*)(h + (long)s0 * 64 + 2 * cl);
    u32 v1 = *(const u32*)(h + (long)s1 * 64 + 2 * cl);
    a0 += b2f((u16)(v0 & 0xffffu));
    a1 += b2f((u16)(v0 >> 16));
    b0 += b2f((u16)(v1 & 0xffffu));
    b1 += b2f((u16)(v1 >> 16));
  }
  for (; j + half < end; j += 2) {
    int s = colsrc[j + half];
    u32 v = *(const u32*)(h + (long)s * 64 + 2 * cl);
    a0 += b2f((u16)(v & 0xffffu));
    a1 += b2f((u16)(v >> 16));
  }
  a0 += b0; a1 += b1;
  a0 += __shfl_xor(a0, 32);
  a1 += __shfl_xor(a1, 32);
  if (lane < 32) {
    float inv = 1.f / fmaxf((float)(end - beg), 1.f);
    u32 r = (u32)f2b(a0 * inv) | ((u32)f2b(a1 * inv) << 16);
    *(u32*)(out + (long)node * 64 + 2 * lane) = r;
  }
}

// ================= fused GATv2 (DPP reduce, 4x unroll, scalar row bases) =================
template <bool LAYER1>
__global__ __launch_bounds__(256) void gat_fused(const u16* __restrict__ fsfd,
    const int* __restrict__ rowptr, const int* __restrict__ colsrc,
    const float* __restrict__ attn, const float* __restrict__ bias,
    const float* __restrict__ drop, void* __restrict__ outv) {
  int node = blockIdx.x * 4 + (threadIdx.x >> 6);
  int lane = threadIdx.x & 63;
  float2 av = *(const float2*)(attn + 2 * lane);
  const int off = 2 * lane;
  u32 fdv = *(const u32*)(fsfd + (size_t)node * 256 + 128 + off);
  float fd0 = b2f((u16)(fdv & 0xffffu)), fd1 = b2f((u16)(fdv >> 16));
  float d_own = 0.f, acc0 = 0.f, acc1 = 0.f;
  const int beg = rowptr[node], end = rowptr[node + 1];
  int j = beg;
  for (; j + 4 <= end; j += 4) {
    const u16* p0 = fsfd + (size_t)__builtin_amdgcn_readfirstlane(colsrc[j])     * 256;
    const u16* p1 = fsfd + (size_t)__builtin_amdgcn_readfirstlane(colsrc[j + 1]) * 256;
    const u16* p2 = fsfd + (size_t)__builtin_amdgcn_readfirstlane(colsrc[j + 2]) * 256;
    const u16* p3 = fsfd + (size_t)__builtin_amdgcn_readfirstlane(colsrc[j + 3]) * 256;
    u32 v0 = *(const u32*)(p0 + off);
    u32 v1 = *(const u32*)(p1 + off);
    u32 v2 = *(const u32*)(p2 + off);
    u32 v3 = *(const u32*)(p3 + off);
    float f00 = b2f((u16)(v0 & 0xffffu)), f01 = b2f((u16)(v0 >> 16));
    float f10 = b2f((u16)(v1 & 0xffffu)), f11 = b2f((u16)(v1 >> 16));
    float f20 = b2f((u16)(v2 & 0xffffu)), f21 = b2f((u16)(v2 >> 16));
    float f30 = b2f((u16)(v3 & 0xffffu)), f31 = b2f((u16)(v3 >> 16));
    float x00 = f00 + fd0; x00 = fmaxf(x00, 0.2f * x00);
    float x01 = f01 + fd1; x01 = fmaxf(x01, 0.2f * x01);
    float x10 = f10 + fd0; x10 = fmaxf(x10, 0.2f * x10);
    float x11 = f11 + fd1; x11 = fmaxf(x11, 0.2f * x11);
    float x20 = f20 + fd0; x20 = fmaxf(x20, 0.2f * x20);
    float x21 = f21 + fd1; x21 = fmaxf(x21, 0.2f * x21);
    float x30 = f30 + fd0; x30 = fmaxf(x30, 0.2f * x30);
    float x31 = f31 + fd1; x31 = fmaxf(x31, 0.2f * x31);
    float c0 = half_reduce(x00 * av.x + x01 * av.y);
    float c1 = half_reduce(x10 * av.x + x11 * av.y);
    float c2 = half_reduce(x20 * av.x + x21 * av.y);
    float c3 = half_reduce(x30 * av.x + x31 * av.y);
    float e0 = __expf(c0), e1 = __expf(c1), e2 = __expf(c2), e3 = __expf(c3);
    d_own += (e0 + e1) + (e2 + e3);
    acc0 += e0 * f00 + e1 * f10 + e2 * f20 + e3 * f30;
    acc1 += e0 * f01 + e1 * f11 + e2 * f21 + e3 * f31;
  }
  for (; j < end; ++j) {
    const u16* p = fsfd + (size_t)__builtin_amdgcn_readfirstlane(colsrc[j]) * 256;
    u32 fv = *(const u32*)(p + off);
    float f0 = b2f((u16)(fv & 0xffffu)), f1 = b2f((u16)(fv >> 16));
    float x0 = f0 + fd0; x0 = fmaxf(x0, 0.2f * x0);
    float x1 = f1 + fd1; x1 = fmaxf(x1, 0.2f * x1);
    float c = half_reduce(x0 * av.x + x1 * av.y);
    float e = __expf(c);
    d_own += e;
    acc0 += e * f0;
    acc1 += e * f1;
  }
  float2 bv = *(const float2*)(bias + 2 * lane);
  float inv = d_own > 0.f ? 1.f / d_own : 0.f;
  float g0 = gelu_f(bv.x + acc0 * inv);
  float g1 = gelu_f(bv.y + acc1 * inv);
  float v0 = 0.5f * (g0 + __shfl_xor(g0, 32));
  float v1 = 0.5f * (g1 + __shfl_xor(g1, 32));
  if constexpr (LAYER1) {
    if (lane < 32) {
      float2 dv = *(const float2*)(drop + (long)node * 64 + 2 * lane);
      u32 r = (u32)f2b(v0 * dv.x) | ((u32)f2b(v1 * dv.y) << 16);
      *(u32*)((u16*)outv + (long)node * 64 + 2 * lane) = r;
    }
  } else {
    float ss = v0 * v0 + v1 * v1;
#pragma unroll
    for (int o = 16; o; o >>= 1) ss += __shfl_xor(ss, o);
    float sc = 1.f / fmaxf(sqrtf(ss), 1e-12f);
    if (lane < 32) {
      float2 r; r.x = v0 * sc; r.y = v1 * sc;
      *(float2*)((float*)outv + (long)node * 64 + 2 * lane) = r;
    }
  }
}

extern "C" void kernel_launch(void* const* d_in, const int* in_sizes, int n_in,
                              void* d_out, int out_size, void* d_ws, size_t ws_size,
                              hipStream_t stream) {
  const float* feat = (const float*)d_in[0];
  const int*   esrc = (const int*)d_in[1];
  const int*   edst = (const int*)d_in[2];
  const float* Wmt = (const float*)d_in[3],  *bmt = (const float*)d_in[4];
  const float* Wms = (const float*)d_in[5],  *bms = (const float*)d_in[6];
  const float* W1s = (const float*)d_in[7],  *W1n = (const float*)d_in[8],  *b1 = (const float*)d_in[9];
  const float* W2s = (const float*)d_in[10], *W2n = (const float*)d_in[11], *b2 = (const float*)d_in[12];
  const float* g1Ws = (const float*)d_in[13], *g1Wd = (const float*)d_in[14];
  const float* g1a  = (const float*)d_in[15], *g1b  = (const float*)d_in[16];
  const float* g2Ws = (const float*)d_in[17], *g2Wd = (const float*)d_in[18];
  const float* g2a  = (const float*)d_in[19], *g2b  = (const float*)d_in[20];
  const float* W3  = (const float*)d_in[21], *b3 = (const float*)d_in[22];
  const float* dropt = (const float*)d_in[23], *drops = (const float*)d_in[24];

  float* out_t = (float*)d_out;
  float* out_s = out_t + (long)N_ * 64;

  // workspace (u16 units)
  u16* wsh = (u16*)d_ws;
  u16* featbf = wsh;                 // N*128
  u16* hbuf_t = wsh +  6400000;      // N*128
  u16* hbuf_s = wsh + 12800000;      // N*128
  u16* hn     = wsh + 19200000;      // N*128
  u16* h1     = wsh + 25600000;      // N*64
  u16* hn2    = wsh + 28800000;      // N*64
  u16* h2     = wsh + 32000000;      // N*64
  u16* hs1    = wsh + 35200000;      // N*64
  u16* fsfd   = wsh + 38400000;      // N*256
  u16* Wpk    = wsh + 51200000;      // 118784
  int* degi   = (int*)(wsh + 51318784);  // N
  int* cursor = degi + N_;               // N
  int* rowptr = cursor + N_;             // N+1
  int* colsrc = rowptr + N_ + 1;         // E
  int* bsum   = colsrc + E_;             // NB_
  int* bpre   = bsum + NB_;              // NB_+1

  const u16* WpMT = Wpk;             // [Wmt|Wms] fused
  const u16* WpS1 = Wpk + 32768;
  const u16* WpS2 = Wpk + 49152;
  const u16* WpG1 = Wpk + 57344;
  const u16* WpG2 = Wpk + 90112;
  const u16* WpW3 = Wpk + 106496;

  constexpr int GB = (N_ + 63) / 64;

  // ---- CSR + packing ----
  (void)hipMemsetAsync(degi, 0, (size_t)(2 * N_) * sizeof(int), stream);
  deg_int_kernel<<<(E_ + 255) / 256, 256, 0, stream>>>(edst, degi);
  scan_local<<<NB_, 256, 0, stream>>>(degi, rowptr, bsum);
  scan_block<<<1, 256, 0, stream>>>(bsum, bpre);
  scan_add<<<(N_ + 256) / 256, 256, 0, stream>>>(rowptr, bpre);
  csr_fill<<<(E_ + 255) / 256, 256, 0, stream>>>(esrc, edst, rowptr, cursor, colsrc);
  pack_feat<<<N_ * 128 / 4 / 256, 256, 0, stream>>>(feat, featbf);
  pack_w<<<464, 256, 0, stream>>>(Wmt, Wms, W1s, W1n, W2s, W2n,
                                  g1Ws, g1Wd, g2Ws, g2Wd, W3, Wpk);

  // ---- both feature masks in one GEMM ----
  gemm_mfma<128, 0, 256, 5><<<GB, 256, 0, stream>>>(featbf, nullptr, WpMT, bmt, bms,
                                                    nullptr, hbuf_t, hbuf_s);

  // ---- topology branch (SAGE) ----
  gather_bf128<<<N_ / 4, 256, 0, stream>>>(hbuf_t, rowptr, colsrc, hn);
  gemm_mfma<128, 128, 64, 2><<<GB, 256, 0, stream>>>(hbuf_t, hn, WpS1, b1, nullptr,
                                                     dropt, h1, nullptr);
  gather_bf64<<<N_ / 4, 256, 0, stream>>>(h1, rowptr, colsrc, hn2);
  gemm_mfma<64, 64, 64, 3><<<GB, 256, 0, stream>>>(h1, hn2, WpS2, b2, nullptr,
                                                   nullptr, h2, nullptr);
  gemm_mfma<64, 128, 64, 4><<<GB, 256, 0, stream>>>(h2, featbf, WpW3, b3, nullptr,
                                                    nullptr, out_t, nullptr);

  // ---- semantic branch (GATv2) ----
  gemm_mfma<128, 0, 256, 0><<<GB, 256, 0, stream>>>(hbuf_s, nullptr, WpG1, nullptr, nullptr,
                                                    nullptr, fsfd, nullptr);
  gat_fused<true><<<N_ / 4, 256, 0, stream>>>(fsfd, rowptr, colsrc, g1a, g1b, drops, hs1);
  gemm_mfma<64, 0, 256, 0><<<GB, 256, 0, stream>>>(hs1, nullptr, WpG2, nullptr, nullptr,
                                                   nullptr, fsfd, nullptr);
  gat_fused<false><<<N_ / 4, 256, 0, stream>>>(fsfd, rowptr, colsrc, g2a, g2b, nullptr, out_s);
}

// Round 11
// 274.567 us; speedup vs baseline: 1.0202x; 1.0202x over previous
//
#include <hip/hip_runtime.h>
#include <math.h>

constexpr int N_  = 50000;
constexpr int E_  = 500000;
constexpr int NB_ = (N_ + 255) / 256;   // 196 scan blocks

typedef unsigned short u16;
typedef unsigned int u32;
typedef short short8 __attribute__((ext_vector_type(8)));
typedef __bf16 bf16x8 __attribute__((ext_vector_type(8)));
typedef float f32x4 __attribute__((ext_vector_type(4)));
typedef short short4v __attribute__((ext_vector_type(4)));

#define DINL __device__ __forceinline__

DINL float gelu_f(float x) { return 0.5f * x * (1.f + erff(x * 0.70710678118654752f)); }
DINL float sigmoid_f(float x) { return 1.f / (1.f + expf(-x)); }
DINL u16 f2b(float x) {            // f32 -> bf16 RNE
  unsigned u = __float_as_uint(x);
  return (u16)((u + 0x7FFFu + ((u >> 16) & 1u)) >> 16);
}
DINL float b2f(u16 b) { return __uint_as_float(((unsigned)b) << 16); }

template <int CTRL>
DINL float dpp_add(float c) {
  int p = __builtin_amdgcn_update_dpp(0, __builtin_bit_cast(int, c), CTRL, 0xf, 0xf, false);
  return c + __builtin_bit_cast(float, p);
}
// sum over each 16-lane group: xor1, xor2, mirror7, mirror15 — all DPP (VALU pipe)
DINL float reduce16(float c) {
  c = dpp_add<0xB1>(c);    // quad_perm [1,0,3,2] : xor1
  c = dpp_add<0x4E>(c);    // quad_perm [2,3,0,1] : xor2
  c = dpp_add<0x141>(c);   // row_half_mirror    : i^7 (xor4 at 4-group level)
  c = dpp_add<0x140>(c);   // row_mirror         : i^15 (xor8 at 8-group level)
  return c;
}

// ================= CSR build =================
__global__ void deg_int_kernel(const int* __restrict__ dst, int* __restrict__ deg) {
  int t = blockIdx.x * 256 + threadIdx.x;
  if (t < E_) atomicAdd(&deg[dst[t]], 1);
}

__global__ __launch_bounds__(256) void scan_local(const int* __restrict__ deg,
    int* __restrict__ rowptr, int* __restrict__ bsum) {
  __shared__ int sums[4];
  const int tid = threadIdx.x, lane = tid & 63, wid = tid >> 6;
  const int i = blockIdx.x * 256 + tid;
  int v = (i < N_) ? deg[i] : 0;
  int x = v;
#pragma unroll
  for (int o = 1; o < 64; o <<= 1) { int y = __shfl_up(x, o); if (lane >= o) x += y; }
  if (lane == 63) sums[wid] = x;
  __syncthreads();
  int woff = 0;
#pragma unroll
  for (int w = 0; w < 3; ++w) if (w < wid) woff += sums[w];
  if (i < N_) rowptr[i] = x - v + woff;
  if (tid == 255) bsum[blockIdx.x] = woff + x;
}

__global__ __launch_bounds__(256) void scan_block(const int* __restrict__ bsum,
                                                  int* __restrict__ bpre) {
  __shared__ int sums[4];
  const int tid = threadIdx.x, lane = tid & 63, wid = tid >> 6;
  int v = (tid < NB_) ? bsum[tid] : 0;
  int x = v;
#pragma unroll
  for (int o = 1; o < 64; o <<= 1) { int y = __shfl_up(x, o); if (lane >= o) x += y; }
  if (lane == 63) sums[wid] = x;
  __syncthreads();
  int woff = 0;
#pragma unroll
  for (int w = 0; w < 3; ++w) if (w < wid) woff += sums[w];
  if (tid < NB_) bpre[tid] = x - v + woff;
  if (tid == 255) bpre[NB_] = woff + x;
}

__global__ __launch_bounds__(256) void scan_add(int* __restrict__ rowptr,
                                                const int* __restrict__ bpre) {
  int i = blockIdx.x * 256 + threadIdx.x;
  if (i < N_) rowptr[i] += bpre[i >> 8];
  else if (i == N_) rowptr[N_] = bpre[NB_];
}

__global__ void csr_fill(const int* __restrict__ src, const int* __restrict__ dst,
                         const int* __restrict__ rowptr, int* __restrict__ cursor,
                         int* __restrict__ colsrc) {
  int e = blockIdx.x * 256 + threadIdx.x;
  if (e >= E_) return;
  int d = dst[e];
  int pos = rowptr[d] + atomicAdd(&cursor[d], 1);
  colsrc[pos] = src[e];
}

// ================= packing =================
__global__ __launch_bounds__(256) void pack_feat(const float* __restrict__ f,
                                                 u16* __restrict__ o) {
  int t = blockIdx.x * 256 + threadIdx.x;
  float4 v = ((const float4*)f)[t];
  short4v r;
  r[0] = (short)f2b(v.x); r[1] = (short)f2b(v.y);
  r[2] = (short)f2b(v.z); r[3] = (short)f2b(v.w);
  ((short4v*)o)[t] = r;
}

// pack weights into MFMA fragment order:
// dst[((ct*(K/32)+ks)*64+lane)*8+j] = W[ks*32+(lane>>4)*8+j][ct*16+(lane&15)]
__global__ __launch_bounds__(256) void pack_w(
    const float* __restrict__ Wmt, const float* __restrict__ Wms,
    const float* __restrict__ W1s, const float* __restrict__ W1n,
    const float* __restrict__ W2s, const float* __restrict__ W2n,
    const float* __restrict__ g1Ws, const float* __restrict__ g1Wd,
    const float* __restrict__ g2Ws, const float* __restrict__ g2Wd,
    const float* __restrict__ W3, u16* __restrict__ dst) {
  int e = blockIdx.x * 256 + threadIdx.x;
  const float *Wa, *Wb = nullptr;
  int K1, K2 = 0, Ca, Cb = 0, st;
  if (e < 16384)       { Wa = Wmt;  K1 = 128; Ca = 128;           st = 0; }
  else if (e < 32768)  { Wa = Wms;  K1 = 128; Ca = 128;           st = 16384; }
  else if (e < 49152)  { Wa = W1s;  Wb = W1n; K1 = 128; K2 = 128; Ca = 64;  st = 32768; }
  else if (e < 57344)  { Wa = W2s;  Wb = W2n; K1 = 64;  K2 = 64;  Ca = 64;  st = 49152; }
  else if (e < 90112)  { Wa = g1Ws; Wb = g1Wd; K1 = 128; Ca = 128; Cb = 128; st = 57344; }
  else if (e < 106496) { Wa = g2Ws; Wb = g2Wd; K1 = 64;  Ca = 128; Cb = 128; st = 90112; }
  else                 { Wa = W3;   K1 = 192; Ca = 64;            st = 106496; }
  int el = e - st;
  int Kt = K1 + K2;
  int ct = el / (Kt * 16);
  int rem = el - ct * Kt * 16;
  int ks = rem >> 9, rem2 = rem & 511, lane = rem2 >> 3, j = rem2 & 7;
  int k = ks * 32 + ((lane >> 4) << 3) + j;
  int c = ct * 16 + (lane & 15);
  float v;
  if (k < K1) v = (c < Ca) ? Wa[k * Ca + c] : Wb[k * Cb + (c - Ca)];
  else        v = Wb[(k - K1) * Ca + c];
  dst[e] = f2b(v);
}

// ================= MFMA GEMM (unchanged from R9) =================
template <int K1, int K2, int C, int EPI>
__global__ __launch_bounds__(256) void gemm_mfma(
    const u16* __restrict__ A1, const u16* __restrict__ A2,
    const u16* __restrict__ Wp, const float* __restrict__ bias,
    const float* __restrict__ bias2, const float* __restrict__ mulf,
    void* __restrict__ outv, void* __restrict__ outv2) {
  constexpr int K = K1 + K2, KS = K / 32, CT4 = C / 64;
  constexpr int NCH1 = K1 / 8, NCH2 = K2 / 8;
  __shared__ u16 alds[64 * K];
  const int tid = threadIdx.x;
  const int w = tid >> 6, l = tid & 63;
  const int wr0 = blockIdx.x * 64;

  short8 wfrag[KS][CT4];
#pragma unroll
  for (int ks = 0; ks < KS; ++ks)
#pragma unroll
    for (int c4 = 0; c4 < CT4; ++c4)
      wfrag[ks][c4] = *(const short8*)(Wp +
          ((size_t)((w * CT4 + c4) * KS + ks) * 64 + l) * 8);

  for (int i = tid; i < 64 * NCH1; i += 256) {
    int rr = i / NCH1, kc = i % NCH1;
    int gr = wr0 + rr; if (gr >= N_) gr = N_ - 1;
    short8 v = *(const short8*)(A1 + (long)gr * K1 + kc * 8);
    *(short8*)&alds[rr * K + ((kc ^ (rr & 7)) << 3)] = v;
  }
  if constexpr (K2 > 0) {
    for (int i = tid; i < 64 * NCH2; i += 256) {
      int rr = i / NCH2, kc = i % NCH2;
      int gr = wr0 + rr; if (gr >= N_) gr = N_ - 1;
      short8 v = *(const short8*)(A2 + (long)gr * K2 + kc * 8);
      *(short8*)&alds[rr * K + (((NCH1 + kc) ^ (rr & 7)) << 3)] = v;
    }
  }
  __syncthreads();

  f32x4 acc[4][CT4];
#pragma unroll
  for (int rg = 0; rg < 4; ++rg)
#pragma unroll
    for (int c4 = 0; c4 < CT4; ++c4) acc[rg][c4] = (f32x4){0.f, 0.f, 0.f, 0.f};

#pragma unroll
  for (int ks = 0; ks < KS; ++ks) {
#pragma unroll
    for (int rg = 0; rg < 4; ++rg) {
      const int nr = rg * 16 + (l & 15);
      const int ch = (ks * 4 + (l >> 4)) ^ (nr & 7);
      short8 av = *(const short8*)&alds[nr * K + (ch << 3)];
      bf16x8 bf = __builtin_bit_cast(bf16x8, av);
#pragma unroll
      for (int c4 = 0; c4 < CT4; ++c4)
        acc[rg][c4] = __builtin_amdgcn_mfma_f32_16x16x32_bf16(
            __builtin_bit_cast(bf16x8, wfrag[ks][c4]), bf, acc[rg][c4], 0, 0, 0);
    }
  }

  const int colq = (l >> 4) << 2;
  if constexpr (EPI == 0) {
    u16* out = (u16*)outv;
#pragma unroll
    for (int rg = 0; rg < 4; ++rg) {
      int row = wr0 + rg * 16 + (l & 15);
      if (row >= N_) continue;
#pragma unroll
      for (int c4 = 0; c4 < CT4; ++c4) {
        int colb = (w * CT4 + c4) * 16 + colq;
        short4v s;
#pragma unroll
        for (int r = 0; r < 4; ++r) s[r] = (short)f2b(acc[rg][c4][r]);
        *(short4v*)(out + (long)row * C + colb) = s;
      }
    }
  } else if constexpr (EPI == 2 || EPI == 3) {
    u16* out = (u16*)outv;
    const int colb = w * 16 + colq;
    float4 bv = *(const float4*)(bias + colb);
#pragma unroll
    for (int rg = 0; rg < 4; ++rg) {
      int row = wr0 + rg * 16 + (l & 15);
      if (row >= N_) continue;
      float4 dv;
      if constexpr (EPI == 2) dv = *(const float4*)(mulf + (long)row * C + colb);
      short4v s;
#pragma unroll
      for (int r = 0; r < 4; ++r) {
        float g = gelu_f(acc[rg][0][r] + ((const float*)&bv)[r]);
        if constexpr (EPI == 2) g *= ((const float*)&dv)[r];
        s[r] = (short)f2b(g);
      }
      *(short4v*)(out + (long)row * C + colb) = s;
    }
  } else if constexpr (EPI == 4) {
    __shared__ float ssb[64][4];
    float* out = (float*)outv;
    const int colb = w * 16 + colq;
    float4 bv = *(const float4*)(bias + colb);
    float xv[4][4];
#pragma unroll
    for (int rg = 0; rg < 4; ++rg) {
      float ss = 0.f;
#pragma unroll
      for (int r = 0; r < 4; ++r) {
        float x = acc[rg][0][r] + ((const float*)&bv)[r];
        x = fmaxf(x, 0.01f * x);
        xv[rg][r] = x; ss += x * x;
      }
      ss += __shfl_xor(ss, 16);
      ss += __shfl_xor(ss, 32);
      if (l < 16) ssb[rg * 16 + l][w] = ss;
    }
    __syncthreads();
#pragma unroll
    for (int rg = 0; rg < 4; ++rg) {
      int nl = rg * 16 + (l & 15);
      int row = wr0 + nl;
      if (row >= N_) continue;
      float ss = ssb[nl][0] + ssb[nl][1] + ssb[nl][2] + ssb[nl][3];
      float sc = 1.f / fmaxf(sqrtf(ss), 1e-12f);
      float4 o;
#pragma unroll
      for (int r = 0; r < 4; ++r) ((float*)&o)[r] = xv[rg][r] * sc;
      *(float4*)(out + (long)row * 64 + colb) = o;
    }
  } else {                                  // EPI == 5
#pragma unroll
    for (int c4 = 0; c4 < CT4; ++c4) {
      const int ct = w * CT4 + c4;
      const bool lo = ct < 8;
      u16* op = lo ? (u16*)outv : (u16*)outv2;
      const int ccb = (ct & 7) * 16 + colq;
      float4 bv = *(const float4*)((lo ? bias : bias2) + ccb);
#pragma unroll
      for (int rg = 0; rg < 4; ++rg) {
        int nl = rg * 16 + (l & 15);
        int row = wr0 + nl;
        if (row >= N_) continue;
        int ch = (ccb >> 3) ^ (nl & 7);
        short4v fq = *(const short4v*)&alds[nl * K + (ch << 3) + (ccb & 7)];
        short4v s;
#pragma unroll
        for (int r = 0; r < 4; ++r) {
          float x = acc[rg][c4][r] + ((const float*)&bv)[r];
          float fv = b2f((u16)fq[r]);
          s[r] = (short)f2b(fv * sigmoid_f(x));
        }
        *(short4v*)(op + (long)row * 128 + ccb) = s;
      }
    }
  }
}

// ================= SAGE gather 128: half-split, uint2/lane, 8 edges in flight ====
__global__ __launch_bounds__(256) void gather_bf128(const u16* __restrict__ h,
    const int* __restrict__ rowptr, const int* __restrict__ colsrc,
    u16* __restrict__ out) {
  int node = blockIdx.x * 4 + (threadIdx.x >> 6);
  int l = threadIdx.x & 63;
  int hl = l & 31, half = l >> 5;
  int beg = rowptr[node], end = rowptr[node + 1];
  float inv = 1.f / fmaxf((float)(end - beg), 1.f);
  float a0 = 0.f, a1 = 0.f, a2 = 0.f, a3 = 0.f;
  float b0 = 0.f, b1 = 0.f, b2 = 0.f, b3 = 0.f;
  const int off = 4 * hl;
  int j = beg;
  for (; j + 8 <= end; j += 8) {
    int sa = colsrc[j + half],     sb = colsrc[j + 2 + half];
    int sc = colsrc[j + 4 + half], sd = colsrc[j + 6 + half];
    uint2 va = *(const uint2*)(h + (size_t)sa * 128 + off);
    uint2 vb = *(const uint2*)(h + (size_t)sb * 128 + off);
    uint2 vc = *(const uint2*)(h + (size_t)sc * 128 + off);
    uint2 vd = *(const uint2*)(h + (size_t)sd * 128 + off);
    a0 += b2f((u16)(va.x & 0xffffu)) + b2f((u16)(vc.x & 0xffffu));
    a1 += b2f((u16)(va.x >> 16))     + b2f((u16)(vc.x >> 16));
    a2 += b2f((u16)(va.y & 0xffffu)) + b2f((u16)(vc.y & 0xffffu));
    a3 += b2f((u16)(va.y >> 16))     + b2f((u16)(vc.y >> 16));
    b0 += b2f((u16)(vb.x & 0xffffu)) + b2f((u16)(vd.x & 0xffffu));
    b1 += b2f((u16)(vb.x >> 16))     + b2f((u16)(vd.x >> 16));
    b2 += b2f((u16)(vb.y & 0xffffu)) + b2f((u16)(vd.y & 0xffffu));
    b3 += b2f((u16)(vb.y >> 16))     + b2f((u16)(vd.y >> 16));
  }
  for (; j < end; j += 2) {
    int idx = j + half;
    bool valid = idx < end;
    int s = colsrc[valid ? idx : end - 1];
    uint2 v = *(const uint2*)(h + (size_t)s * 128 + off);
    if (!valid) { v.x = 0; v.y = 0; }
    a0 += b2f((u16)(v.x & 0xffffu));
    a1 += b2f((u16)(v.x >> 16));
    a2 += b2f((u16)(v.y & 0xffffu));
    a3 += b2f((u16)(v.y >> 16));
  }
  a0 += b0; a1 += b1; a2 += b2; a3 += b3;
  a0 += __shfl_xor(a0, 32); a1 += __shfl_xor(a1, 32);
  a2 += __shfl_xor(a2, 32); a3 += __shfl_xor(a3, 32);
  if (l < 32) {
    short4v s;
    s[0] = (short)f2b(a0 * inv); s[1] = (short)f2b(a1 * inv);
    s[2] = (short)f2b(a2 * inv); s[3] = (short)f2b(a3 * inv);
    *(short4v*)(out + (long)node * 128 + off) = s;
  }
}

// ================= SAGE gather 64: quarter-split, 8 edges in flight =============
__global__ __launch_bounds__(256) void gather_bf64(const u16* __restrict__ h,
    const int* __restrict__ rowptr, const int* __restrict__ colsrc,
    u16* __restrict__ out) {
  int node = blockIdx.x * 4 + (threadIdx.x >> 6);
  int l = threadIdx.x & 63;
  int ql = l & 15, qg = l >> 4;      // quarter-lane, quarter-group 0..3
  int beg = rowptr[node], end = rowptr[node + 1];
  float a0 = 0.f, a1 = 0.f, a2 = 0.f, a3 = 0.f;
  float b0 = 0.f, b1 = 0.f, b2 = 0.f, b3 = 0.f;
  const int off = 4 * ql;
  int j = beg;
  for (; j + 8 <= end; j += 8) {
    int s0 = colsrc[j + qg], s1 = colsrc[j + 4 + qg];
    uint2 v0 = *(const uint2*)(h + (size_t)s0 * 64 + off);
    uint2 v1 = *(const uint2*)(h + (size_t)s1 * 64 + off);
    a0 += b2f((u16)(v0.x & 0xffffu));
    a1 += b2f((u16)(v0.x >> 16));
    a2 += b2f((u16)(v0.y & 0xffffu));
    a3 += b2f((u16)(v0.y >> 16));
    b0 += b2f((u16)(v1.x & 0xffffu));
    b1 += b2f((u16)(v1.x >> 16));
    b2 += b2f((u16)(v1.y & 0xffffu));
    b3 += b2f((u16)(v1.y >> 16));
  }
  for (; j < end; j += 4) {
    int idx = j + qg;
    bool valid = idx < end;
    int s = colsrc[valid ? idx : end - 1];
    uint2 v = *(const uint2*)(h + (size_t)s * 64 + off);
    if (!valid) { v.x = 0; v.y = 0; }
    a0 += b2f((u16)(v.x & 0xffffu));
    a1 += b2f((u16)(v.x >> 16));
    a2 += b2f((u16)(v.y & 0xffffu));
    a3 += b2f((u16)(v.y >> 16));
  }
  a0 += b0; a1 += b1; a2 += b2; a3 += b3;
  a0 += __shfl_xor(a0, 32); a1 += __shfl_xor(a1, 32);
  a2 += __shfl_xor(a2, 32); a3 += __shfl_xor(a3, 32);
  a0 += __shfl_xor(a0, 16); a1 += __shfl_xor(a1, 16);
  a2 += __shfl_xor(a2, 16); a3 += __shfl_xor(a3, 16);
  if (l < 16) {
    float inv = 1.f / fmaxf((float)(end - beg), 1.f);
    short4v s;
    s[0] = (short)f2b(a0 * inv); s[1] = (short)f2b(a1 * inv);
    s[2] = (short)f2b(a2 * inv); s[3] = (short)f2b(a3 * inv);
    *(short4v*)(out + (long)node * 64 + off) = s;
  }
}

// ================= fused GATv2: half-split (2 edges/wave-step), 16-lane DPP reduce =
// lane l: hl=l&31 packs 4 cols of head (hl>>4); halves process different edges.
template <bool LAYER1>
__global__ __launch_bounds__(256) void gat_fused(const u16* __restrict__ fsfd,
    const int* __restrict__ rowptr, const int* __restrict__ colsrc,
    const float* __restrict__ attn, const float* __restrict__ bias,
    const float* __restrict__ drop, void* __restrict__ outv) {
  int node = blockIdx.x * 4 + (threadIdx.x >> 6);
  int l = threadIdx.x & 63;
  int hl = l & 31, half = l >> 5;
  const int off = 4 * hl;                         // col offset within 128 (head*64 + 4*qi)
  float4 av = *(const float4*)(attn + off);
  uint2 fdv = *(const uint2*)(fsfd + (size_t)node * 256 + 128 + off);
  float fd0 = b2f((u16)(fdv.x & 0xffffu)), fd1 = b2f((u16)(fdv.x >> 16));
  float fd2 = b2f((u16)(fdv.y & 0xffffu)), fd3 = b2f((u16)(fdv.y >> 16));
  float d_own = 0.f, acc0 = 0.f, acc1 = 0.f, acc2 = 0.f, acc3 = 0.f;

  auto edge = [&](uint2 v, float m) {
    float f0 = b2f((u16)(v.x & 0xffffu)), f1 = b2f((u16)(v.x >> 16));
    float f2 = b2f((u16)(v.y & 0xffffu)), f3 = b2f((u16)(v.y >> 16));
    float t0 = f0 + fd0, t1 = f1 + fd1, t2 = f2 + fd2, t3 = f3 + fd3;
    t0 = fmaxf(t0, 0.2f * t0); t1 = fmaxf(t1, 0.2f * t1);
    t2 = fmaxf(t2, 0.2f * t2); t3 = fmaxf(t3, 0.2f * t3);
    float c = t0 * av.x + t1 * av.y + t2 * av.z + t3 * av.w;
    c = reduce16(c);
    float e = __expf(c) * m;
    d_own += e;
    acc0 += e * f0; acc1 += e * f1; acc2 += e * f2; acc3 += e * f3;
  };

  const int beg = rowptr[node], end = rowptr[node + 1];
  int j = beg;
  for (; j + 8 <= end; j += 8) {
    int sa = colsrc[j + half],     sb = colsrc[j + 2 + half];
    int sc = colsrc[j + 4 + half], sd = colsrc[j + 6 + half];
    uint2 va = *(const uint2*)(fsfd + (size_t)sa * 256 + off);
    uint2 vb = *(const uint2*)(fsfd + (size_t)sb * 256 + off);
    uint2 vc = *(const uint2*)(fsfd + (size_t)sc * 256 + off);
    uint2 vd = *(const uint2*)(fsfd + (size_t)sd * 256 + off);
    edge(va, 1.f); edge(vb, 1.f); edge(vc, 1.f); edge(vd, 1.f);
  }
  for (; j < end; j += 2) {
    int idx = j + half;
    bool valid = idx < end;
    int s = colsrc[valid ? idx : end - 1];
    uint2 v = *(const uint2*)(fsfd + (size_t)s * 256 + off);
    if (!valid) { v.x = 0; v.y = 0; }
    edge(v, valid ? 1.f : 0.f);
  }

  acc0 += __shfl_xor(acc0, 32); acc1 += __shfl_xor(acc1, 32);
  acc2 += __shfl_xor(acc2, 32); acc3 += __shfl_xor(acc3, 32);
  d_own += __shfl_xor(d_own, 32);

  float4 bv = *(const float4*)(bias + off);
  float inv = d_own > 0.f ? 1.f / d_own : 0.f;
  float g0 = gelu_f(bv.x + acc0 * inv);
  float g1 = gelu_f(bv.y + acc1 * inv);
  float g2 = gelu_f(bv.z + acc2 * inv);
  float g3 = gelu_f(bv.w + acc3 * inv);
  // mean over heads: pair lane hl (head0, col 4*qi+r) with hl^16 (head1, same col)
  float v0 = 0.5f * (g0 + __shfl_xor(g0, 16));
  float v1 = 0.5f * (g1 + __shfl_xor(g1, 16));
  float v2 = 0.5f * (g2 + __shfl_xor(g2, 16));
  float v3 = 0.5f * (g3 + __shfl_xor(g3, 16));
  if constexpr (LAYER1) {
    if (l < 16) {
      float4 dv = *(const float4*)(drop + (long)node * 64 + 4 * l);
      short4v s;
      s[0] = (short)f2b(v0 * dv.x); s[1] = (short)f2b(v1 * dv.y);
      s[2] = (short)f2b(v2 * dv.z); s[3] = (short)f2b(v3 * dv.w);
      *(short4v*)((u16*)outv + (long)node * 64 + 4 * l) = s;
    }
  } else {
    float ss = v0 * v0 + v1 * v1 + v2 * v2 + v3 * v3;
    ss = reduce16(ss);
    float sc = 1.f / fmaxf(sqrtf(ss), 1e-12f);
    if (l < 16) {
      float4 o; o.x = v0 * sc; o.y = v1 * sc; o.z = v2 * sc; o.w = v3 * sc;
      *(float4*)((float*)outv + (long)node * 64 + 4 * l) = o;
    }
  }
}

extern "C" void kernel_launch(void* const* d_in, const int* in_sizes, int n_in,
                              void* d_out, int out_size, void* d_ws, size_t ws_size,
                              hipStream_t stream) {
  const float* feat = (const float*)d_in[0];
  const int*   esrc = (const int*)d_in[1];
  const int*   edst = (const int*)d_in[2];
  const float* Wmt = (const float*)d_in[3],  *bmt = (const float*)d_in[4];
  const float* Wms = (const float*)d_in[5],  *bms = (const float*)d_in[6];
  const float* W1s = (const float*)d_in[7],  *W1n = (const float*)d_in[8],  *b1 = (const float*)d_in[9];
  const float* W2s = (const float*)d_in[10], *W2n = (const float*)d_in[11], *b2 = (const float*)d_in[12];
  const float* g1Ws = (const float*)d_in[13], *g1Wd = (const float*)d_in[14];
  const float* g1a  = (const float*)d_in[15], *g1b  = (const float*)d_in[16];
  const float* g2Ws = (const float*)d_in[17], *g2Wd = (const float*)d_in[18];
  const float* g2a  = (const float*)d_in[19], *g2b  = (const float*)d_in[20];
  const float* W3  = (const float*)d_in[21], *b3 = (const float*)d_in[22];
  const float* dropt = (const float*)d_in[23], *drops = (const float*)d_in[24];

  float* out_t = (float*)d_out;
  float* out_s = out_t + (long)N_ * 64;

  // workspace (u16 units)
  u16* wsh = (u16*)d_ws;
  u16* featbf = wsh;                 // N*128
  u16* hbuf_t = wsh +  6400000;      // N*128
  u16* hbuf_s = wsh + 12800000;      // N*128
  u16* hn     = wsh + 19200000;      // N*128
  u16* h1     = wsh + 25600000;      // N*64
  u16* hn2    = wsh + 28800000;      // N*64
  u16* h2     = wsh + 32000000;      // N*64
  u16* hs1    = wsh + 35200000;      // N*64
  u16* fsfd   = wsh + 38400000;      // N*256
  u16* Wpk    = wsh + 51200000;      // 118784
  int* degi   = (int*)(wsh + 51318784);  // N
  int* cursor = degi + N_;               // N
  int* rowptr = cursor + N_;             // N+1
  int* colsrc = rowptr + N_ + 1;         // E
  int* bsum   = colsrc + E_;             // NB_
  int* bpre   = bsum + NB_;              // NB_+1

  const u16* WpMT = Wpk;             // [Wmt|Wms] fused
  const u16* WpS1 = Wpk + 32768;
  const u16* WpS2 = Wpk + 49152;
  const u16* WpG1 = Wpk + 57344;
  const u16* WpG2 = Wpk + 90112;
  const u16* WpW3 = Wpk + 106496;

  constexpr int GB = (N_ + 63) / 64;

  // ---- CSR + packing ----
  (void)hipMemsetAsync(degi, 0, (size_t)(2 * N_) * sizeof(int), stream);
  deg_int_kernel<<<(E_ + 255) / 256, 256, 0, stream>>>(edst, degi);
  scan_local<<<NB_, 256, 0, stream>>>(degi, rowptr, bsum);
  scan_block<<<1, 256, 0, stream>>>(bsum, bpre);
  scan_add<<<(N_ + 256) / 256, 256, 0, stream>>>(rowptr, bpre);
  csr_fill<<<(E_ + 255) / 256, 256, 0, stream>>>(esrc, edst, rowptr, cursor, colsrc);
  pack_feat<<<N_ * 128 / 4 / 256, 256, 0, stream>>>(feat, featbf);
  pack_w<<<464, 256, 0, stream>>>(Wmt, Wms, W1s, W1n, W2s, W2n,
                                  g1Ws, g1Wd, g2Ws, g2Wd, W3, Wpk);

  // ---- both feature masks in one GEMM ----
  gemm_mfma<128, 0, 256, 5><<<GB, 256, 0, stream>>>(featbf, nullptr, WpMT, bmt, bms,
                                                    nullptr, hbuf_t, hbuf_s);

  // ---- topology branch (SAGE) ----
  gather_bf128<<<N_ / 4, 256, 0, stream>>>(hbuf_t, rowptr, colsrc, hn);
  gemm_mfma<128, 128, 64, 2><<<GB, 256, 0, stream>>>(hbuf_t, hn, WpS1, b1, nullptr,
                                                     dropt, h1, nullptr);
  gather_bf64<<<N_ / 4, 256, 0, stream>>>(h1, rowptr, colsrc, hn2);
  gemm_mfma<64, 64, 64, 3><<<GB, 256, 0, stream>>>(h1, hn2, WpS2, b2, nullptr,
                                                   nullptr, h2, nullptr);
  gemm_mfma<64, 128, 64, 4><<<GB, 256, 0, stream>>>(h2, featbf, WpW3, b3, nullptr,
                                                    nullptr, out_t, nullptr);

  // ---- semantic branch (GATv2) ----
  gemm_mfma<128, 0, 256, 0><<<GB, 256, 0, stream>>>(hbuf_s, nullptr, WpG1, nullptr, nullptr,
                                                    nullptr, fsfd, nullptr);
  gat_fused<true><<<N_ / 4, 256, 0, stream>>>(fsfd, rowptr, colsrc, g1a, g1b, drops, hs1);
  gemm_mfma<64, 0, 256, 0><<<GB, 256, 0, stream>>>(hs1, nullptr, WpG2, nullptr, nullptr,
                                                   nullptr, fsfd, nullptr);
  gat_fused<false><<<N_ / 4, 256, 0, stream>>>(fsfd, rowptr, colsrc, g2a, g2b, nullptr, out_s);
}

// Round 12
// 268.916 us; speedup vs baseline: 1.0417x; 1.0210x over previous
//
#include <hip/hip_runtime.h>
#include <math.h>

constexpr int N_  = 50000;
constexpr int E_  = 500000;
constexpr int NB_ = (N_ + 255) / 256;   // 196 scan blocks

typedef unsigned short u16;
typedef unsigned int u32;
typedef short short8 __attribute__((ext_vector_type(8)));
typedef __bf16 bf16x8 __attribute__((ext_vector_type(8)));
typedef float f32x4 __attribute__((ext_vector_type(4)));
typedef short short4v __attribute__((ext_vector_type(4)));

#define DINL __device__ __forceinline__

DINL float gelu_f(float x) { return 0.5f * x * (1.f + erff(x * 0.70710678118654752f)); }
DINL float sigmoid_f(float x) { return 1.f / (1.f + expf(-x)); }
DINL u16 f2b(float x) {            // f32 -> bf16 RNE
  unsigned u = __float_as_uint(x);
  return (u16)((u + 0x7FFFu + ((u >> 16) & 1u)) >> 16);
}
DINL float b2f(u16 b) { return __uint_as_float(((unsigned)b) << 16); }

template <int CTRL>
DINL float dpp_add(float c) {
  int p = __builtin_amdgcn_update_dpp(0, __builtin_bit_cast(int, c), CTRL, 0xf, 0xf, false);
  return c + __builtin_bit_cast(float, p);
}
// sum over each 16-lane group — all DPP (VALU pipe)
DINL float reduce16(float c) {
  c = dpp_add<0xB1>(c);    // quad_perm [1,0,3,2] : xor1
  c = dpp_add<0x4E>(c);    // quad_perm [2,3,0,1] : xor2
  c = dpp_add<0x141>(c);   // row_half_mirror
  c = dpp_add<0x140>(c);   // row_mirror
  return c;
}

// ================= CSR build =================
__global__ void deg_int_kernel(const int* __restrict__ dst, int* __restrict__ deg) {
  int t = blockIdx.x * 256 + threadIdx.x;
  if (t < E_) atomicAdd(&deg[dst[t]], 1);
}

__global__ __launch_bounds__(256) void scan_local(const int* __restrict__ deg,
    int* __restrict__ rowptr, int* __restrict__ bsum) {
  __shared__ int sums[4];
  const int tid = threadIdx.x, lane = tid & 63, wid = tid >> 6;
  const int i = blockIdx.x * 256 + tid;
  int v = (i < N_) ? deg[i] : 0;
  int x = v;
#pragma unroll
  for (int o = 1; o < 64; o <<= 1) { int y = __shfl_up(x, o); if (lane >= o) x += y; }
  if (lane == 63) sums[wid] = x;
  __syncthreads();
  int woff = 0;
#pragma unroll
  for (int w = 0; w < 3; ++w) if (w < wid) woff += sums[w];
  if (i < N_) rowptr[i] = x - v + woff;
  if (tid == 255) bsum[blockIdx.x] = woff + x;
}

__global__ __launch_bounds__(256) void scan_block(const int* __restrict__ bsum,
                                                  int* __restrict__ bpre) {
  __shared__ int sums[4];
  const int tid = threadIdx.x, lane = tid & 63, wid = tid >> 6;
  int v = (tid < NB_) ? bsum[tid] : 0;
  int x = v;
#pragma unroll
  for (int o = 1; o < 64; o <<= 1) { int y = __shfl_up(x, o); if (lane >= o) x += y; }
  if (lane == 63) sums[wid] = x;
  __syncthreads();
  int woff = 0;
#pragma unroll
  for (int w = 0; w < 3; ++w) if (w < wid) woff += sums[w];
  if (tid < NB_) bpre[tid] = x - v + woff;
  if (tid == 255) bpre[NB_] = woff + x;
}

__global__ __launch_bounds__(256) void scan_add(int* __restrict__ rowptr,
                                                const int* __restrict__ bpre) {
  int i = blockIdx.x * 256 + threadIdx.x;
  if (i < N_) rowptr[i] += bpre[i >> 8];
  else if (i == N_) rowptr[N_] = bpre[NB_];
}

__global__ void csr_fill(const int* __restrict__ src, const int* __restrict__ dst,
                         const int* __restrict__ rowptr, int* __restrict__ cursor,
                         int* __restrict__ colsrc) {
  int e = blockIdx.x * 256 + threadIdx.x;
  if (e >= E_) return;
  int d = dst[e];
  int pos = rowptr[d] + atomicAdd(&cursor[d], 1);
  colsrc[pos] = src[e];
}

// ================= packing =================
__global__ __launch_bounds__(256) void pack_feat(const float* __restrict__ f,
                                                 u16* __restrict__ o) {
  int t = blockIdx.x * 256 + threadIdx.x;
  float4 v = ((const float4*)f)[t];
  short4v r;
  r[0] = (short)f2b(v.x); r[1] = (short)f2b(v.y);
  r[2] = (short)f2b(v.z); r[3] = (short)f2b(v.w);
  ((short4v*)o)[t] = r;
}

// pack weights into MFMA fragment order:
// dst[((ct*(K/32)+ks)*64+lane)*8+j] = W[ks*32+(lane>>4)*8+j][ct*16+(lane&15)]
__global__ __launch_bounds__(256) void pack_w(
    const float* __restrict__ Wmt, const float* __restrict__ Wms,
    const float* __restrict__ W1s, const float* __restrict__ W1n,
    const float* __restrict__ W2s, const float* __restrict__ W2n,
    const float* __restrict__ g1Ws, const float* __restrict__ g1Wd,
    const float* __restrict__ g2Ws, const float* __restrict__ g2Wd,
    const float* __restrict__ W3, u16* __restrict__ dst) {
  int e = blockIdx.x * 256 + threadIdx.x;
  const float *Wa, *Wb = nullptr;
  int K1, K2 = 0, Ca, Cb = 0, st;
  if (e < 16384)       { Wa = Wmt;  K1 = 128; Ca = 128;           st = 0; }
  else if (e < 32768)  { Wa = Wms;  K1 = 128; Ca = 128;           st = 16384; }
  else if (e < 49152)  { Wa = W1s;  Wb = W1n; K1 = 128; K2 = 128; Ca = 64;  st = 32768; }
  else if (e < 57344)  { Wa = W2s;  Wb = W2n; K1 = 64;  K2 = 64;  Ca = 64;  st = 49152; }
  else if (e < 90112)  { Wa = g1Ws; Wb = g1Wd; K1 = 128; Ca = 128; Cb = 128; st = 57344; }
  else if (e < 106496) { Wa = g2Ws; Wb = g2Wd; K1 = 64;  Ca = 128; Cb = 128; st = 90112; }
  else                 { Wa = W3;   K1 = 192; Ca = 64;            st = 106496; }
  int el = e - st;
  int Kt = K1 + K2;
  int ct = el / (Kt * 16);
  int rem = el - ct * Kt * 16;
  int ks = rem >> 9, rem2 = rem & 511, lane = rem2 >> 3, j = rem2 & 7;
  int k = ks * 32 + ((lane >> 4) << 3) + j;
  int c = ct * 16 + (lane & 15);
  float v;
  if (k < K1) v = (c < Ca) ? Wa[k * Ca + c] : Wb[k * Cb + (c - Ca)];
  else        v = Wb[(k - K1) * Ca + c];
  dst[e] = f2b(v);
}

// ================= MFMA GEMM (8 waves: col-quadrant x row-half split) =============
// wave w: cq = w>>1 owns cols [cq*C/4,(cq+1)*C/4); rh = w&1 owns row-groups rh*2,rh*2+1.
// Swapped operands (W as MFMA A), D transposed -> contiguous short4/float4 stores.
// LDS XOR-swizzled: 16B-chunk index ^= (row & 7).
template <int K1, int K2, int C, int EPI>
__global__ __launch_bounds__(512) void gemm_mfma(
    const u16* __restrict__ A1, const u16* __restrict__ A2,
    const u16* __restrict__ Wp, const float* __restrict__ bias,
    const float* __restrict__ bias2, const float* __restrict__ mulf,
    void* __restrict__ outv, void* __restrict__ outv2) {
  constexpr int K = K1 + K2, KS = K / 32, CT4 = C / 64;
  constexpr int NCH1 = K1 / 8, NCH2 = K2 / 8;
  __shared__ u16 alds[64 * K];
  const int tid = threadIdx.x;
  const int w = tid >> 6, l = tid & 63;
  const int cq = w >> 1, rh = w & 1;
  const int wr0 = blockIdx.x * 64;

  short8 wfrag[KS][CT4];
#pragma unroll
  for (int ks = 0; ks < KS; ++ks)
#pragma unroll
    for (int c4 = 0; c4 < CT4; ++c4)
      wfrag[ks][c4] = *(const short8*)(Wp +
          ((size_t)((cq * CT4 + c4) * KS + ks) * 64 + l) * 8);

  for (int i = tid; i < 64 * NCH1; i += 512) {
    int rr = i / NCH1, kc = i % NCH1;
    int gr = wr0 + rr; if (gr >= N_) gr = N_ - 1;
    short8 v = *(const short8*)(A1 + (long)gr * K1 + kc * 8);
    *(short8*)&alds[rr * K + ((kc ^ (rr & 7)) << 3)] = v;
  }
  if constexpr (K2 > 0) {
    for (int i = tid; i < 64 * NCH2; i += 512) {
      int rr = i / NCH2, kc = i % NCH2;
      int gr = wr0 + rr; if (gr >= N_) gr = N_ - 1;
      short8 v = *(const short8*)(A2 + (long)gr * K2 + kc * 8);
      *(short8*)&alds[rr * K + (((NCH1 + kc) ^ (rr & 7)) << 3)] = v;
    }
  }
  __syncthreads();

  f32x4 acc[2][CT4];
#pragma unroll
  for (int rr = 0; rr < 2; ++rr)
#pragma unroll
    for (int c4 = 0; c4 < CT4; ++c4) acc[rr][c4] = (f32x4){0.f, 0.f, 0.f, 0.f};

#pragma unroll
  for (int ks = 0; ks < KS; ++ks) {
#pragma unroll
    for (int rr = 0; rr < 2; ++rr) {
      const int nr = (rh * 2 + rr) * 16 + (l & 15);
      const int ch = (ks * 4 + (l >> 4)) ^ (nr & 7);
      short8 av = *(const short8*)&alds[nr * K + (ch << 3)];
      bf16x8 bf = __builtin_bit_cast(bf16x8, av);
#pragma unroll
      for (int c4 = 0; c4 < CT4; ++c4)
        acc[rr][c4] = __builtin_amdgcn_mfma_f32_16x16x32_bf16(
            __builtin_bit_cast(bf16x8, wfrag[ks][c4]), bf, acc[rr][c4], 0, 0, 0);
    }
  }

  const int colq = (l >> 4) << 2;
  if constexpr (EPI == 0) {
    u16* out = (u16*)outv;
#pragma unroll
    for (int rr = 0; rr < 2; ++rr) {
      int row = wr0 + (rh * 2 + rr) * 16 + (l & 15);
      if (row >= N_) continue;
#pragma unroll
      for (int c4 = 0; c4 < CT4; ++c4) {
        int colb = (cq * CT4 + c4) * 16 + colq;
        short4v s;
#pragma unroll
        for (int r = 0; r < 4; ++r) s[r] = (short)f2b(acc[rr][c4][r]);
        *(short4v*)(out + (long)row * C + colb) = s;
      }
    }
  } else if constexpr (EPI == 2 || EPI == 3) {
    u16* out = (u16*)outv;
    const int colb = cq * 16 + colq;         // CT4 == 1
    float4 bv = *(const float4*)(bias + colb);
#pragma unroll
    for (int rr = 0; rr < 2; ++rr) {
      int row = wr0 + (rh * 2 + rr) * 16 + (l & 15);
      if (row >= N_) continue;
      float4 dv;
      if constexpr (EPI == 2) dv = *(const float4*)(mulf + (long)row * C + colb);
      short4v s;
#pragma unroll
      for (int r = 0; r < 4; ++r) {
        float g = gelu_f(acc[rr][0][r] + ((const float*)&bv)[r]);
        if constexpr (EPI == 2) g *= ((const float*)&dv)[r];
        s[r] = (short)f2b(g);
      }
      *(short4v*)(out + (long)row * C + colb) = s;
    }
  } else if constexpr (EPI == 4) {          // C=64: leaky + row l2norm (f32 out)
    __shared__ float ssb[64][4];
    float* out = (float*)outv;
    const int colb = cq * 16 + colq;
    float4 bv = *(const float4*)(bias + colb);
    float xv[2][4];
#pragma unroll
    for (int rr = 0; rr < 2; ++rr) {
      float ss = 0.f;
#pragma unroll
      for (int r = 0; r < 4; ++r) {
        float x = acc[rr][0][r] + ((const float*)&bv)[r];
        x = fmaxf(x, 0.01f * x);
        xv[rr][r] = x; ss += x * x;
      }
      ss += __shfl_xor(ss, 16);
      ss += __shfl_xor(ss, 32);
      if (l < 16) ssb[(rh * 2 + rr) * 16 + l][cq] = ss;
    }
    __syncthreads();
#pragma unroll
    for (int rr = 0; rr < 2; ++rr) {
      int nl = (rh * 2 + rr) * 16 + (l & 15);
      int row = wr0 + nl;
      if (row >= N_) continue;
      float ss = ssb[nl][0] + ssb[nl][1] + ssb[nl][2] + ssb[nl][3];
      float sc = 1.f / fmaxf(sqrtf(ss), 1e-12f);
      float4 o;
#pragma unroll
      for (int r = 0; r < 4; ++r) ((float*)&o)[r] = xv[rr][r] * sc;
      *(float4*)(out + (long)row * 64 + colb) = o;
    }
  } else {                                  // EPI == 5: dual mask (C=256, K=128)
#pragma unroll
    for (int c4 = 0; c4 < CT4; ++c4) {
      const int ct = cq * CT4 + c4;
      const bool lo = ct < 8;
      u16* op = lo ? (u16*)outv : (u16*)outv2;
      const int ccb = (ct & 7) * 16 + colq;
      float4 bv = *(const float4*)((lo ? bias : bias2) + ccb);
#pragma unroll
      for (int rr = 0; rr < 2; ++rr) {
        int nl = (rh * 2 + rr) * 16 + (l & 15);
        int row = wr0 + nl;
        if (row >= N_) continue;
        int ch = (ccb >> 3) ^ (nl & 7);
        short4v fq = *(const short4v*)&alds[nl * K + (ch << 3) + (ccb & 7)];
        short4v s;
#pragma unroll
        for (int r = 0; r < 4; ++r) {
          float x = acc[rr][c4][r] + ((const float*)&bv)[r];
          float fv = b2f((u16)fq[r]);
          s[r] = (short)f2b(fv * sigmoid_f(x));
        }
        *(short4v*)(op + (long)row * 128 + ccb) = s;
      }
    }
  }
}

// ================= SAGE gather 128: half-split, uint2/lane, 8 edges in flight ====
__global__ __launch_bounds__(256) void gather_bf128(const u16* __restrict__ h,
    const int* __restrict__ rowptr, const int* __restrict__ colsrc,
    u16* __restrict__ out) {
  int node = blockIdx.x * 4 + (threadIdx.x >> 6);
  int l = threadIdx.x & 63;
  int hl = l & 31, half = l >> 5;
  int beg = rowptr[node], end = rowptr[node + 1];
  float inv = 1.f / fmaxf((float)(end - beg), 1.f);
  float a0 = 0.f, a1 = 0.f, a2 = 0.f, a3 = 0.f;
  float b0 = 0.f, b1 = 0.f, b2 = 0.f, b3 = 0.f;
  const int off = 4 * hl;
  int j = beg;
  for (; j + 8 <= end; j += 8) {
    int sa = colsrc[j + half],     sb = colsrc[j + 2 + half];
    int sc = colsrc[j + 4 + half], sd = colsrc[j + 6 + half];
    uint2 va = *(const uint2*)(h + (size_t)sa * 128 + off);
    uint2 vb = *(const uint2*)(h + (size_t)sb * 128 + off);
    uint2 vc = *(const uint2*)(h + (size_t)sc * 128 + off);
    uint2 vd = *(const uint2*)(h + (size_t)sd * 128 + off);
    a0 += b2f((u16)(va.x & 0xffffu)) + b2f((u16)(vc.x & 0xffffu));
    a1 += b2f((u16)(va.x >> 16))     + b2f((u16)(vc.x >> 16));
    a2 += b2f((u16)(va.y & 0xffffu)) + b2f((u16)(vc.y & 0xffffu));
    a3 += b2f((u16)(va.y >> 16))     + b2f((u16)(vc.y >> 16));
    b0 += b2f((u16)(vb.x & 0xffffu)) + b2f((u16)(vd.x & 0xffffu));
    b1 += b2f((u16)(vb.x >> 16))     + b2f((u16)(vd.x >> 16));
    b2 += b2f((u16)(vb.y & 0xffffu)) + b2f((u16)(vd.y & 0xffffu));
    b3 += b2f((u16)(vb.y >> 16))     + b2f((u16)(vd.y >> 16));
  }
  for (; j < end; j += 2) {
    int idx = j + half;
    bool valid = idx < end;
    int s = colsrc[valid ? idx : end - 1];
    uint2 v = *(const uint2*)(h + (size_t)s * 128 + off);
    if (!valid) { v.x = 0; v.y = 0; }
    a0 += b2f((u16)(v.x & 0xffffu));
    a1 += b2f((u16)(v.x >> 16));
    a2 += b2f((u16)(v.y & 0xffffu));
    a3 += b2f((u16)(v.y >> 16));
  }
  a0 += b0; a1 += b1; a2 += b2; a3 += b3;
  a0 += __shfl_xor(a0, 32); a1 += __shfl_xor(a1, 32);
  a2 += __shfl_xor(a2, 32); a3 += __shfl_xor(a3, 32);
  if (l < 32) {
    short4v s;
    s[0] = (short)f2b(a0 * inv); s[1] = (short)f2b(a1 * inv);
    s[2] = (short)f2b(a2 * inv); s[3] = (short)f2b(a3 * inv);
    *(short4v*)(out + (long)node * 128 + off) = s;
  }
}

// ================= SAGE gather 64: quarter-split, 8 edges in flight =============
__global__ __launch_bounds__(256) void gather_bf64(const u16* __restrict__ h,
    const int* __restrict__ rowptr, const int* __restrict__ colsrc,
    u16* __restrict__ out) {
  int node = blockIdx.x * 4 + (threadIdx.x >> 6);
  int l = threadIdx.x & 63;
  int ql = l & 15, qg = l >> 4;
  int beg = rowptr[node], end = rowptr[node + 1];
  float a0 = 0.f, a1 = 0.f, a2 = 0.f, a3 = 0.f;
  float b0 = 0.f, b1 = 0.f, b2 = 0.f, b3 = 0.f;
  const int off = 4 * ql;
  int j = beg;
  for (; j + 8 <= end; j += 8) {
    int s0 = colsrc[j + qg], s1 = colsrc[j + 4 + qg];
    uint2 v0 = *(const uint2*)(h + (size_t)s0 * 64 + off);
    uint2 v1 = *(const uint2*)(h + (size_t)s1 * 64 + off);
    a0 += b2f((u16)(v0.x & 0xffffu));
    a1 += b2f((u16)(v0.x >> 16));
    a2 += b2f((u16)(v0.y & 0xffffu));
    a3 += b2f((u16)(v0.y >> 16));
    b0 += b2f((u16)(v1.x & 0xffffu));
    b1 += b2f((u16)(v1.x >> 16));
    b2 += b2f((u16)(v1.y & 0xffffu));
    b3 += b2f((u16)(v1.y >> 16));
  }
  for (; j < end; j += 4) {
    int idx = j + qg;
    bool valid = idx < end;
    int s = colsrc[valid ? idx : end - 1];
    uint2 v = *(const uint2*)(h + (size_t)s * 64 + off);
    if (!valid) { v.x = 0; v.y = 0; }
    a0 += b2f((u16)(v.x & 0xffffu));
    a1 += b2f((u16)(v.x >> 16));
    a2 += b2f((u16)(v.y & 0xffffu));
    a3 += b2f((u16)(v.y >> 16));
  }
  a0 += b0; a1 += b1; a2 += b2; a3 += b3;
  a0 += __shfl_xor(a0, 32); a1 += __shfl_xor(a1, 32);
  a2 += __shfl_xor(a2, 32); a3 += __shfl_xor(a3, 32);
  a0 += __shfl_xor(a0, 16); a1 += __shfl_xor(a1, 16);
  a2 += __shfl_xor(a2, 16); a3 += __shfl_xor(a3, 16);
  if (l < 16) {
    float inv = 1.f / fmaxf((float)(end - beg), 1.f);
    short4v s;
    s[0] = (short)f2b(a0 * inv); s[1] = (short)f2b(a1 * inv);
    s[2] = (short)f2b(a2 * inv); s[3] = (short)f2b(a3 * inv);
    *(short4v*)(out + (long)node * 64 + off) = s;
  }
}

// ================= fused GATv2: half-split, 16-lane DPP reduce ===================
template <bool LAYER1>
__global__ __launch_bounds__(256) void gat_fused(const u16* __restrict__ fsfd,
    const int* __restrict__ rowptr, const int* __restrict__ colsrc,
    const float* __restrict__ attn, const float* __restrict__ bias,
    const float* __restrict__ drop, void* __restrict__ outv) {
  int node = blockIdx.x * 4 + (threadIdx.x >> 6);
  int l = threadIdx.x & 63;
  int hl = l & 31, half = l >> 5;
  const int off = 4 * hl;
  float4 av = *(const float4*)(attn + off);
  uint2 fdv = *(const uint2*)(fsfd + (size_t)node * 256 + 128 + off);
  float fd0 = b2f((u16)(fdv.x & 0xffffu)), fd1 = b2f((u16)(fdv.x >> 16));
  float fd2 = b2f((u16)(fdv.y & 0xffffu)), fd3 = b2f((u16)(fdv.y >> 16));
  float d_own = 0.f, acc0 = 0.f, acc1 = 0.f, acc2 = 0.f, acc3 = 0.f;

  auto edge = [&](uint2 v, float m) {
    float f0 = b2f((u16)(v.x & 0xffffu)), f1 = b2f((u16)(v.x >> 16));
    float f2 = b2f((u16)(v.y & 0xffffu)), f3 = b2f((u16)(v.y >> 16));
    float t0 = f0 + fd0, t1 = f1 + fd1, t2 = f2 + fd2, t3 = f3 + fd3;
    t0 = fmaxf(t0, 0.2f * t0); t1 = fmaxf(t1, 0.2f * t1);
    t2 = fmaxf(t2, 0.2f * t2); t3 = fmaxf(t3, 0.2f * t3);
    float c = t0 * av.x + t1 * av.y + t2 * av.z + t3 * av.w;
    c = reduce16(c);
    float e = __expf(c) * m;
    d_own += e;
    acc0 += e * f0; acc1 += e * f1; acc2 += e * f2; acc3 += e * f3;
  };

  const int beg = rowptr[node], end = rowptr[node + 1];
  int j = beg;
  for (; j + 8 <= end; j += 8) {
    int sa = colsrc[j + half],     sb = colsrc[j + 2 + half];
    int sc = colsrc[j + 4 + half], sd = colsrc[j + 6 + half];
    uint2 va = *(const uint2*)(fsfd + (size_t)sa * 256 + off);
    uint2 vb = *(const uint2*)(fsfd + (size_t)sb * 256 + off);
    uint2 vc = *(const uint2*)(fsfd + (size_t)sc * 256 + off);
    uint2 vd = *(const uint2*)(fsfd + (size_t)sd * 256 + off);
    edge(va, 1.f); edge(vb, 1.f); edge(vc, 1.f); edge(vd, 1.f);
  }
  for (; j < end; j += 2) {
    int idx = j + half;
    bool valid = idx < end;
    int s = colsrc[valid ? idx : end - 1];
    uint2 v = *(const uint2*)(fsfd + (size_t)s * 256 + off);
    if (!valid) { v.x = 0; v.y = 0; }
    edge(v, valid ? 1.f : 0.f);
  }

  acc0 += __shfl_xor(acc0, 32); acc1 += __shfl_xor(acc1, 32);
  acc2 += __shfl_xor(acc2, 32); acc3 += __shfl_xor(acc3, 32);
  d_own += __shfl_xor(d_own, 32);

  float4 bv = *(const float4*)(bias + off);
  float inv = d_own > 0.f ? 1.f / d_own : 0.f;
  float g0 = gelu_f(bv.x + acc0 * inv);
  float g1 = gelu_f(bv.y + acc1 * inv);
  float g2 = gelu_f(bv.z + acc2 * inv);
  float g3 = gelu_f(bv.w + acc3 * inv);
  float v0 = 0.5f * (g0 + __shfl_xor(g0, 16));
  float v1 = 0.5f * (g1 + __shfl_xor(g1, 16));
  float v2 = 0.5f * (g2 + __shfl_xor(g2, 16));
  float v3 = 0.5f * (g3 + __shfl_xor(g3, 16));
  if constexpr (LAYER1) {
    if (l < 16) {
      float4 dv = *(const float4*)(drop + (long)node * 64 + 4 * l);
      short4v s;
      s[0] = (short)f2b(v0 * dv.x); s[1] = (short)f2b(v1 * dv.y);
      s[2] = (short)f2b(v2 * dv.z); s[3] = (short)f2b(v3 * dv.w);
      *(short4v*)((u16*)outv + (long)node * 64 + 4 * l) = s;
    }
  } else {
    float ss = v0 * v0 + v1 * v1 + v2 * v2 + v3 * v3;
    ss = reduce16(ss);
    float sc = 1.f / fmaxf(sqrtf(ss), 1e-12f);
    if (l < 16) {
      float4 o; o.x = v0 * sc; o.y = v1 * sc; o.z = v2 * sc; o.w = v3 * sc;
      *(float4*)((float*)outv + (long)node * 64 + 4 * l) = o;
    }
  }
}

extern "C" void kernel_launch(void* const* d_in, const int* in_sizes, int n_in,
                              void* d_out, int out_size, void* d_ws, size_t ws_size,
                              hipStream_t stream) {
  const float* feat = (const float*)d_in[0];
  const int*   esrc = (const int*)d_in[1];
  const int*   edst = (const int*)d_in[2];
  const float* Wmt = (const float*)d_in[3],  *bmt = (const float*)d_in[4];
  const float* Wms = (const float*)d_in[5],  *bms = (const float*)d_in[6];
  const float* W1s = (const float*)d_in[7],  *W1n = (const float*)d_in[8],  *b1 = (const float*)d_in[9];
  const float* W2s = (const float*)d_in[10], *W2n = (const float*)d_in[11], *b2 = (const float*)d_in[12];
  const float* g1Ws = (const float*)d_in[13], *g1Wd = (const float*)d_in[14];
  const float* g1a  = (const float*)d_in[15], *g1b  = (const float*)d_in[16];
  const float* g2Ws = (const float*)d_in[17], *g2Wd = (const float*)d_in[18];
  const float* g2a  = (const float*)d_in[19], *g2b  = (const float*)d_in[20];
  const float* W3  = (const float*)d_in[21], *b3 = (const float*)d_in[22];
  const float* dropt = (const float*)d_in[23], *drops = (const float*)d_in[24];

  float* out_t = (float*)d_out;
  float* out_s = out_t + (long)N_ * 64;

  // workspace (u16 units)
  u16* wsh = (u16*)d_ws;
  u16* featbf = wsh;                 // N*128
  u16* hbuf_t = wsh +  6400000;      // N*128
  u16* hbuf_s = wsh + 12800000;      // N*128
  u16* hn     = wsh + 19200000;      // N*128
  u16* h1     = wsh + 25600000;      // N*64
  u16* hn2    = wsh + 28800000;      // N*64
  u16* h2     = wsh + 32000000;      // N*64
  u16* hs1    = wsh + 35200000;      // N*64
  u16* fsfd   = wsh + 38400000;      // N*256
  u16* Wpk    = wsh + 51200000;      // 118784
  int* degi   = (int*)(wsh + 51318784);  // N
  int* cursor = degi + N_;               // N
  int* rowptr = cursor + N_;             // N+1
  int* colsrc = rowptr + N_ + 1;         // E
  int* bsum   = colsrc + E_;             // NB_
  int* bpre   = bsum + NB_;              // NB_+1

  const u16* WpMT = Wpk;             // [Wmt|Wms] fused
  const u16* WpS1 = Wpk + 32768;
  const u16* WpS2 = Wpk + 49152;
  const u16* WpG1 = Wpk + 57344;
  const u16* WpG2 = Wpk + 90112;
  const u16* WpW3 = Wpk + 106496;

  constexpr int GB = (N_ + 63) / 64;

  // ---- CSR + packing ----
  (void)hipMemsetAsync(degi, 0, (size_t)(2 * N_) * sizeof(int), stream);
  deg_int_kernel<<<(E_ + 255) / 256, 256, 0, stream>>>(edst, degi);
  scan_local<<<NB_, 256, 0, stream>>>(degi, rowptr, bsum);
  scan_block<<<1, 256, 0, stream>>>(bsum, bpre);
  scan_add<<<(N_ + 256) / 256, 256, 0, stream>>>(rowptr, bpre);
  csr_fill<<<(E_ + 255) / 256, 256, 0, stream>>>(esrc, edst, rowptr, cursor, colsrc);
  pack_feat<<<N_ * 128 / 4 / 256, 256, 0, stream>>>(feat, featbf);
  pack_w<<<464, 256, 0, stream>>>(Wmt, Wms, W1s, W1n, W2s, W2n,
                                  g1Ws, g1Wd, g2Ws, g2Wd, W3, Wpk);

  // ---- both feature masks in one GEMM ----
  gemm_mfma<128, 0, 256, 5><<<GB, 512, 0, stream>>>(featbf, nullptr, WpMT, bmt, bms,
                                                    nullptr, hbuf_t, hbuf_s);

  // ---- topology branch (SAGE) ----
  gather_bf128<<<N_ / 4, 256, 0, stream>>>(hbuf_t, rowptr, colsrc, hn);
  gemm_mfma<128, 128, 64, 2><<<GB, 512, 0, stream>>>(hbuf_t, hn, WpS1, b1, nullptr,
                                                     dropt, h1, nullptr);
  gather_bf64<<<N_ / 4, 256, 0, stream>>>(h1, rowptr, colsrc, hn2);
  gemm_mfma<64, 64, 64, 3><<<GB, 512, 0, stream>>>(h1, hn2, WpS2, b2, nullptr,
                                                   nullptr, h2, nullptr);
  gemm_mfma<64, 128, 64, 4><<<GB, 512, 0, stream>>>(h2, featbf, WpW3, b3, nullptr,
                                                    nullptr, out_t, nullptr);

  // ---- semantic branch (GATv2) ----
  gemm_mfma<128, 0, 256, 0><<<GB, 512, 0, stream>>>(hbuf_s, nullptr, WpG1, nullptr, nullptr,
                                                    nullptr, fsfd, nullptr);
  gat_fused<true><<<N_ / 4, 256, 0, stream>>>(fsfd, rowptr, colsrc, g1a, g1b, drops, hs1);
  gemm_mfma<64, 0, 256, 0><<<GB, 512, 0, stream>>>(hs1, nullptr, WpG2, nullptr, nullptr,
                                                   nullptr, fsfd, nullptr);
  gat_fused<false><<<N_ / 4, 256, 0, stream>>>(fsfd, rowptr, colsrc, g2a, g2b, nullptr, out_s);
}